// Round 4
// baseline (414.480 us; speedup 1.0000x reference)
//
#include <hip/hip_runtime.h>
#include <hip/hip_bf16.h>

typedef __attribute__((ext_vector_type(8))) short short8;
typedef __attribute__((ext_vector_type(4))) float f32x4;
typedef unsigned short u16;
typedef unsigned int u32;

#define NROWS 16384
#define KDIM 16384
#define EPS 1e-6f

__device__ __forceinline__ u16 f2bf(float x) {
    union { float f; u32 u; } v; v.f = x;
    u32 u = v.u;
    u32 r = (u + 0x7FFFu + ((u >> 16) & 1u)) >> 16;  // RNE
    return (u16)r;
}

__device__ __forceinline__ void glds16(const void* g, void* l) {
    __builtin_amdgcn_global_load_lds(
        (const __attribute__((address_space(1))) void*)g,
        (__attribute__((address_space(3))) void*)l, 16, 0, 0);
}

__device__ __forceinline__ short cvbf(float x) {
    __hip_bfloat16 h = __float2bfloat16(x);
    return *(short*)&h;
}

__device__ __forceinline__ short8 cvt8(float4 a, float4 b) {
    short8 r = { cvbf(a.x), cvbf(a.y), cvbf(a.z), cvbf(a.w),
                 cvbf(b.x), cvbf(b.y), cvbf(b.z), cvbf(b.w) };
    return r;
}

// ---------------- Stage 0: transpose weight -> Wt[64][256] ----------------
__global__ __launch_bounds__(256) void wt_kernel(const float* __restrict__ W,
                                                 float* __restrict__ Wt) {
    int idx = blockIdx.x * 256 + threadIdx.x;  // 16384
    int k = idx >> 6, c = idx & 63;
    Wt[c * 256 + k] = W[idx];
}

// ---------------- Stage 1: support = input @ W (fp32) ---------------------
__global__ __launch_bounds__(256) void support_kernel(
    const float* __restrict__ inp, const float* __restrict__ Wt,
    float* __restrict__ sup)
{
    int tid = threadIdx.x;
    int col = tid & 63;
    int rr = tid >> 6;                        // 0..3
    int rowbase = blockIdx.x * 32 + rr * 8;   // 8 rows per thread
    const float4* wt4 = (const float4*)(Wt + (size_t)col * 256);
    float acc[8];
#pragma unroll
    for (int i = 0; i < 8; ++i) acc[i] = 0.f;
    for (int k4 = 0; k4 < 64; ++k4) {
        float4 wv = wt4[k4];
#pragma unroll
        for (int i = 0; i < 8; ++i) {
            float4 iv = *((const float4*)(inp + (size_t)(rowbase + i) * 256) + k4);
            acc[i] += iv.x * wv.x + iv.y * wv.y + iv.z * wv.z + iv.w * wv.w;
        }
    }
#pragma unroll
    for (int i = 0; i < 8; ++i)
        sup[(size_t)(rowbase + i) * 64 + col] = acc[i];
}

// ---------------- Stage 2: global min ------------------------------------
__global__ __launch_bounds__(256) void min_part_kernel(
    const float* __restrict__ sup, float* __restrict__ partmin)
{
    __shared__ float wmin[4];
    int tid = threadIdx.x;
    const float4* s4 = (const float4*)sup;
    size_t idx = (size_t)blockIdx.x * 256 + tid;
    float m = 3.4e38f;
#pragma unroll
    for (int j = 0; j < 4; ++j) {
        float4 v = s4[idx + (size_t)j * 65536];
        m = fminf(m, fminf(fminf(v.x, v.y), fminf(v.z, v.w)));
    }
#pragma unroll
    for (int off = 32; off; off >>= 1) m = fminf(m, __shfl_down(m, off, 64));
    if ((tid & 63) == 0) wmin[tid >> 6] = m;
    __syncthreads();
    if (tid == 0)
        partmin[blockIdx.x] = fminf(fminf(wmin[0], wmin[1]), fminf(wmin[2], wmin[3]));
}

__global__ __launch_bounds__(256) void min_final_kernel(
    const float* __restrict__ partmin, float* __restrict__ mu)
{
    __shared__ float wmin[4];
    int tid = threadIdx.x;
    float m = partmin[tid];
#pragma unroll
    for (int off = 32; off; off >>= 1) m = fminf(m, __shfl_down(m, off, 64));
    if ((tid & 63) == 0) wmin[tid >> 6] = m;
    __syncthreads();
    if (tid == 0)
        mu[0] = fminf(fminf(wmin[0], wmin[1]), fminf(wmin[2], wmin[3]));
}

// ---------------- Stage 3: Bt[n][k] bf16; n<64: s^(p+1), n>=64: s^p -------
__global__ __launch_bounds__(256) void build_bt_kernel(
    const float* __restrict__ sup, const float* __restrict__ muptr,
    const int* __restrict__ pptr, u16* __restrict__ Bt)
{
    int k = blockIdx.x * 256 + threadIdx.x;   // 0..16383
    float mu = *muptr;
    int p = *pptr;
    const float4* srow = (const float4*)(sup + (size_t)k * 64);
#pragma unroll
    for (int j = 0; j < 16; ++j) {
        float4 v = srow[j];
        float ss[4] = {v.x, v.y, v.z, v.w};
#pragma unroll
        for (int q = 0; q < 4; ++q) {
            int c = j * 4 + q;
            float s = ss[q] - mu + EPS;
            float d = 1.f;
            for (int i = 0; i < p; ++i) d *= s;   // s^p
            Bt[(size_t)c * KDIM + k] = f2bf(d * s);          // top
            Bt[(size_t)(c + 64) * KDIM + k] = f2bf(d);       // down
        }
    }
}

// ---------------- Stage 4: GEMM partials, K-split=2 -----------------------
// BM=32, BN=128 (64 top | 64 down), BK=32, 256 thr (4 waves, 2M x 2N).
// Grid 1024 -> 4 blocks/CU resident (4 independent barrier domains,
// 16 waves/CU). All staging via global_load_lds (linear dest,
// inverse-swizzled global source); A stays f32 in LDS, cvt on read.
// Round-robin XCD dispatch + h=blockIdx&1 means each XCD touches only
// one 2MB Bt half -> L2-resident.
#define BM 32
#define BN 128
#define BK 32
#define KH 8192
#define NTI 256   // KH/BK

__global__ __launch_bounds__(256, 4) void gemm_kernel(
    const float* __restrict__ adj, const u16* __restrict__ Bt,
    float* __restrict__ Pp)
{
    __shared__ __align__(16) float Ash[2][BM * BK];   // 4 KB x2 (f32)
    __shared__ __align__(16) u16  Bsh[2][BN * BK];    // 8 KB x2 (bf16)

    const int tid = threadIdx.x;
    const int rb = blockIdx.x >> 1;
    const int h  = blockIdx.x & 1;
    const size_t rowbase = (size_t)rb * BM;
    const size_t kbase   = (size_t)h * KH;

    // --- A staging: 256 granules (16B = 4 floats), 8 granules/row
    const int ar = tid >> 3;
    const int ax = (tid & 7) ^ (ar & 7);          // inverse-swizzled source
    const float* asrc = adj + (rowbase + ar) * KDIM + kbase + ax * 4;

    // --- B staging: 512 granules (16B = 8 bf16), 4 granules/row
    const int g0 = tid, g1 = tid + 256;
    const int bn0 = g0 >> 2, bx0 = (g0 & 3) ^ (bn0 & 3);
    const int bn1 = g1 >> 2, bx1 = (g1 & 3) ^ (bn1 & 3);
    const u16* bsrc0 = Bt + (size_t)bn0 * KDIM + kbase + bx0 * 8;
    const u16* bsrc1 = Bt + (size_t)bn1 * KDIM + kbase + bx1 * 8;

    // --- compute indices: 4 waves = 2M x 2N
    const int lane = tid & 63;
    const int w    = tid >> 6;
    const int wm   = w >> 1;                // 0..1 : 16-row tile
    const int wn   = w & 1;                 // 0..1 : 32-col group
    const int l15  = lane & 15, lg = lane >> 4;
    const int ar0  = wm * 16 + l15;         // A frag row
    const int asw  = ar0 & 7;
    const int n0   = wn * 32 + l15;         // top cols n0, n1; down +64
    const int n1   = n0 + 16;
    const int bs0  = n0 & 3, bs1 = n1 & 3;  // (n+64)&3 == n&3

    f32x4 acc0 = {0.f, 0.f, 0.f, 0.f};
    f32x4 acc1 = acc0, acc2 = acc0, acc3 = acc0;

    auto stage = [&](int kt, int buf) {
        const int koff = kt * BK;
        char* ab = (char*)Ash[buf];
        char* bb = (char*)Bsh[buf];
        glds16(asrc + koff, ab + tid * 16);
        glds16(bsrc0 + koff, bb + g0 * 16);
        glds16(bsrc1 + koff, bb + g1 * 16);
    };

    stage(0, 0);

    for (int t = 0; t < NTI; ++t) {
        __syncthreads();                 // tile t resident in buf[t&1]
        if (t + 1 < NTI) stage(t + 1, (t + 1) & 1);
        const float4* As4 = (const float4*)Ash[t & 1];
        const short8* Bs8 = (const short8*)Bsh[t & 1];
        float4 fa = As4[ar0 * 8 + ((lg * 2    ) ^ asw)];
        float4 fb = As4[ar0 * 8 + ((lg * 2 + 1) ^ asw)];
        short8 a  = cvt8(fa, fb);
        short8 b0 = Bs8[n0 * 4 + (lg ^ bs0)];
        short8 b1 = Bs8[n1 * 4 + (lg ^ bs1)];
        short8 b2 = Bs8[(n0 + 64) * 4 + (lg ^ bs0)];
        short8 b3 = Bs8[(n1 + 64) * 4 + (lg ^ bs1)];
        acc0 = __builtin_amdgcn_mfma_f32_16x16x32_bf16(a, b0, acc0, 0, 0, 0);
        acc1 = __builtin_amdgcn_mfma_f32_16x16x32_bf16(a, b1, acc1, 0, 0, 0);
        acc2 = __builtin_amdgcn_mfma_f32_16x16x32_bf16(a, b2, acc2, 0, 0, 0);
        acc3 = __builtin_amdgcn_mfma_f32_16x16x32_bf16(a, b3, acc3, 0, 0, 0);
    }

    // partial store: [block][32 rows][128 cols]; C: col=l15(+base), row=lg*4+q
    float* pb = Pp + (size_t)blockIdx.x * (BM * BN);
#pragma unroll
    for (int q = 0; q < 4; ++q) {
        int r = wm * 16 + lg * 4 + q;
        pb[r * BN + n0]      = acc0[q];
        pb[r * BN + n1]      = acc1[q];
        pb[r * BN + n0 + 64] = acc2[q];
        pb[r * BN + n1 + 64] = acc3[q];
    }
}

// ---------------- Stage 5: combine K-halves, ratio + mu + bias ------------
// Pp layout: block b=(rb,h): rb = b>>1, h = b&1; [b][32][128]
__global__ __launch_bounds__(256) void reduce_kernel(
    const float* __restrict__ Pp, const float* __restrict__ bias,
    const float* __restrict__ muptr, float* __restrict__ out)
{
    int idx = blockIdx.x * 256 + threadIdx.x;   // 1M outputs
    int r = idx >> 6, c = idx & 63;
    int rb = r >> 5, rr = r & 31;
    const float* p0 = Pp + (size_t)(rb * 2) * (BM * BN) + rr * BN + c;
    const float* p1 = p0 + BM * BN;
    float T = p0[0]  + p1[0];
    float D = p0[64] + p1[64];
    out[idx] = T / D + muptr[0] + bias[c];
}

extern "C" void kernel_launch(void* const* d_in, const int* in_sizes, int n_in,
                              void* d_out, int out_size, void* d_ws, size_t ws_size,
                              hipStream_t stream)
{
    const float* inp  = (const float*)d_in[0];
    const float* adj  = (const float*)d_in[1];
    const float* W    = (const float*)d_in[2];
    const float* bias = (const float*)d_in[3];
    const int*   p    = (const int*)d_in[4];
    float* out = (float*)d_out;

    // ws layout: Bt 4MB | partmin 1KB | mu | Wt 64KB | (8MB:) Pp 16MB
    char* ws = (char*)d_ws;
    u16*   Bt      = (u16*)ws;
    float* partmin = (float*)(ws + (size_t)4 * 1024 * 1024);
    float* mu      = partmin + 256;
    float* Wt      = (float*)(ws + (size_t)4 * 1024 * 1024 + 4096);
    float* Pp      = (float*)(ws + (size_t)8 * 1024 * 1024);

    float* sup = out;   // park support in d_out; reduce overwrites at the end

    wt_kernel       <<<64,   256, 0, stream>>>(W, Wt);
    support_kernel  <<<512,  256, 0, stream>>>(inp, Wt, sup);
    min_part_kernel <<<256,  256, 0, stream>>>(sup, partmin);
    min_final_kernel<<<1,    256, 0, stream>>>(partmin, mu);
    build_bt_kernel <<<64,   256, 0, stream>>>(sup, mu, p, Bt);
    gemm_kernel     <<<1024, 256, 0, stream>>>(adj, Bt, Pp);
    reduce_kernel   <<<4096, 256, 0, stream>>>(Pp, bias, mu, out);
}

// Round 5
// 411.328 us; speedup vs baseline: 1.0077x; 1.0077x over previous
//
#include <hip/hip_runtime.h>
#include <hip/hip_bf16.h>

typedef __attribute__((ext_vector_type(8))) short short8;
typedef __attribute__((ext_vector_type(4))) float f32x4;
typedef unsigned short u16;
typedef unsigned int u32;

#define NROWS 16384
#define KDIM 16384
#define EPS 1e-6f

__device__ __forceinline__ u16 f2bf(float x) {
    union { float f; u32 u; } v; v.f = x;
    u32 u = v.u;
    u32 r = (u + 0x7FFFu + ((u >> 16) & 1u)) >> 16;  // RNE
    return (u16)r;
}

__device__ __forceinline__ void glds16(const void* g, void* l) {
    __builtin_amdgcn_global_load_lds(
        (const __attribute__((address_space(1))) void*)g,
        (__attribute__((address_space(3))) void*)l, 16, 0, 0);
}

__device__ __forceinline__ short cvbf(float x) {
    __hip_bfloat16 h = __float2bfloat16(x);
    return *(short*)&h;
}

__device__ __forceinline__ short8 cvt8(float4 a, float4 b) {
    short8 r = { cvbf(a.x), cvbf(a.y), cvbf(a.z), cvbf(a.w),
                 cvbf(b.x), cvbf(b.y), cvbf(b.z), cvbf(b.w) };
    return r;
}

// ---------------- Stage 0: transpose weight -> Wt[64][256] ----------------
__global__ __launch_bounds__(256) void wt_kernel(const float* __restrict__ W,
                                                 float* __restrict__ Wt) {
    int idx = blockIdx.x * 256 + threadIdx.x;  // 16384
    int k = idx >> 6, c = idx & 63;
    Wt[c * 256 + k] = W[idx];
}

// ---------------- Stage 1: support = input @ W (fp32) ---------------------
__global__ __launch_bounds__(256) void support_kernel(
    const float* __restrict__ inp, const float* __restrict__ Wt,
    float* __restrict__ sup)
{
    int tid = threadIdx.x;
    int col = tid & 63;
    int rr = tid >> 6;                        // 0..3
    int rowbase = blockIdx.x * 32 + rr * 8;   // 8 rows per thread
    const float4* wt4 = (const float4*)(Wt + (size_t)col * 256);
    float acc[8];
#pragma unroll
    for (int i = 0; i < 8; ++i) acc[i] = 0.f;
    for (int k4 = 0; k4 < 64; ++k4) {
        float4 wv = wt4[k4];
#pragma unroll
        for (int i = 0; i < 8; ++i) {
            float4 iv = *((const float4*)(inp + (size_t)(rowbase + i) * 256) + k4);
            acc[i] += iv.x * wv.x + iv.y * wv.y + iv.z * wv.z + iv.w * wv.w;
        }
    }
#pragma unroll
    for (int i = 0; i < 8; ++i)
        sup[(size_t)(rowbase + i) * 64 + col] = acc[i];
}

// ---------------- Stage 2: global min ------------------------------------
__global__ __launch_bounds__(256) void min_part_kernel(
    const float* __restrict__ sup, float* __restrict__ partmin)
{
    __shared__ float wmin[4];
    int tid = threadIdx.x;
    const float4* s4 = (const float4*)sup;
    size_t idx = (size_t)blockIdx.x * 256 + tid;
    float m = 3.4e38f;
#pragma unroll
    for (int j = 0; j < 4; ++j) {
        float4 v = s4[idx + (size_t)j * 65536];
        m = fminf(m, fminf(fminf(v.x, v.y), fminf(v.z, v.w)));
    }
#pragma unroll
    for (int off = 32; off; off >>= 1) m = fminf(m, __shfl_down(m, off, 64));
    if ((tid & 63) == 0) wmin[tid >> 6] = m;
    __syncthreads();
    if (tid == 0)
        partmin[blockIdx.x] = fminf(fminf(wmin[0], wmin[1]), fminf(wmin[2], wmin[3]));
}

__global__ __launch_bounds__(256) void min_final_kernel(
    const float* __restrict__ partmin, float* __restrict__ mu)
{
    __shared__ float wmin[4];
    int tid = threadIdx.x;
    float m = partmin[tid];
#pragma unroll
    for (int off = 32; off; off >>= 1) m = fminf(m, __shfl_down(m, off, 64));
    if ((tid & 63) == 0) wmin[tid >> 6] = m;
    __syncthreads();
    if (tid == 0)
        mu[0] = fminf(fminf(wmin[0], wmin[1]), fminf(wmin[2], wmin[3]));
}

// ---------------- Stage 3: Bt[n][k] bf16; n<64: s^(p+1), n>=64: s^p -------
__global__ __launch_bounds__(256) void build_bt_kernel(
    const float* __restrict__ sup, const float* __restrict__ muptr,
    const int* __restrict__ pptr, u16* __restrict__ Bt)
{
    int k = blockIdx.x * 256 + threadIdx.x;   // 0..16383
    float mu = *muptr;
    int p = *pptr;
    const float4* srow = (const float4*)(sup + (size_t)k * 64);
#pragma unroll
    for (int j = 0; j < 16; ++j) {
        float4 v = srow[j];
        float ss[4] = {v.x, v.y, v.z, v.w};
#pragma unroll
        for (int q = 0; q < 4; ++q) {
            int c = j * 4 + q;
            float s = ss[q] - mu + EPS;
            float d = 1.f;
            for (int i = 0; i < p; ++i) d *= s;   // s^p
            Bt[(size_t)c * KDIM + k] = f2bf(d * s);          // top
            Bt[(size_t)(c + 64) * KDIM + k] = f2bf(d);       // down
        }
    }
}

// ---------------- Stage 4: GEMM partials, K-split=2 -----------------------
// R2 structure (BM=64, BN=128, BK=64, 512 thr, glds staging, 4Mx2N waves)
// + depth-2 pipeline: 3 LDS buffers, counted s_waitcnt vmcnt(4), raw
// s_barrier (never drain vmcnt to 0 in the main loop). 1 block/CU (96 KB).
#define BM 64
#define BN 128
#define BK 64
#define KH 8192
#define NTI 128   // KH/BK
#define NBUF 3

__global__ __launch_bounds__(512, 2) void gemm_kernel(
    const float* __restrict__ adj, const u16* __restrict__ Bt,
    float* __restrict__ Pp)
{
    __shared__ __align__(16) float Ash[NBUF][BM * BK];   // 16 KB x3 (f32)
    __shared__ __align__(16) u16  Bsh[NBUF][BN * BK];    // 16 KB x3 (bf16)

    const int tid = threadIdx.x;
    const int rb = blockIdx.x >> 1;
    const int h  = blockIdx.x & 1;
    const size_t rowbase = (size_t)rb * BM;
    const size_t kbase = (size_t)h * KH;

    // --- staging: thread handles granules g = tid and tid+512 (16 B each)
    const int ga0 = tid,        ga1 = tid + 512;
    const int ar0 = ga0 >> 4,   ax0 = (ga0 & 15) ^ (ar0 & 7);
    const int ar1 = ga1 >> 4,   ax1 = (ga1 & 15) ^ (ar1 & 7);
    const float* asrc0 = adj + (rowbase + ar0) * KDIM + kbase + ax0 * 4;
    const float* asrc1 = adj + (rowbase + ar1) * KDIM + kbase + ax1 * 4;
    const int bn0 = ga0 >> 3,   bx0 = (ga0 & 7) ^ (bn0 & 7);
    const int bn1 = ga1 >> 3,   bx1 = (ga1 & 7) ^ (bn1 & 7);
    const u16* bsrc0 = Bt + (size_t)bn0 * KDIM + kbase + bx0 * 8;
    const u16* bsrc1 = Bt + (size_t)bn1 * KDIM + kbase + bx1 * 8;

    // --- compute indices: 8 waves = 4M x 2N
    const int lane = tid & 63;
    const int w    = tid >> 6;
    const int wm   = w >> 1;        // 0..3 : row tile
    const int wn   = w & 1;         // 0..1 : col half
    const int l15  = lane & 15, lg = lane >> 4;
    const int arow = wm * 16 + l15;
    const int asw  = arow & 7;

    f32x4 acc[4];
#pragma unroll
    for (int j = 0; j < 4; ++j) acc[j] = (f32x4){0.f, 0.f, 0.f, 0.f};

    auto stage = [&](int kt, int buf) {
        const int koff = kt * BK;
        char* ab = (char*)Ash[buf];
        char* bb = (char*)Bsh[buf];
        glds16(asrc0 + koff, ab + ga0 * 16);
        glds16(asrc1 + koff, ab + ga1 * 16);
        glds16(bsrc0 + koff, bb + ga0 * 16);
        glds16(bsrc1 + koff, bb + ga1 * 16);
    };

    // prologue: tiles 0 and 1 in flight (8 glds outstanding)
    stage(0, 0);
    stage(1, 1);

    int b0 = 0, b1 = 1, b2 = 2;   // buf of tile t, t+1, t+2
    for (int t = 0; t < NTI; ++t) {
        // wait ONLY for tile t's 4 glds (leave tile t+1's 4 in flight)
        if (t < NTI - 1) {
            asm volatile("s_waitcnt vmcnt(4)" ::: "memory");
        } else {
            asm volatile("s_waitcnt vmcnt(0)" ::: "memory");
        }
        __builtin_amdgcn_s_barrier();          // all waves: tile t resident
        __builtin_amdgcn_sched_barrier(0);     // no ds_read hoisted above
        if (t + 2 < NTI) stage(t + 2, b2);     // depth-2 prefetch
        const float4* As4 = (const float4*)Ash[b0];
        const short8* Bs8 = (const short8*)Bsh[b0];
#pragma unroll
        for (int ks = 0; ks < 2; ++ks) {
            const int x0 = ks * 8 + lg * 2;
            float4 fa = As4[arow * 16 + ((x0    ) ^ asw)];
            float4 fb = As4[arow * 16 + ((x0 + 1) ^ asw)];
            short8 a = cvt8(fa, fb);
            const int bx = ks * 4 + lg;
#pragma unroll
            for (int j = 0; j < 4; ++j) {
                const int n = wn * 32 + (j & 1) * 16 + (j >> 1) * 64 + l15;
                short8 b = Bs8[n * 8 + (bx ^ (n & 7))];
                acc[j] = __builtin_amdgcn_mfma_f32_16x16x32_bf16(a, b, acc[j], 0, 0, 0);
            }
        }
        int tmp = b0; b0 = b1; b1 = b2; b2 = tmp;   // rotate buffers
    }

    // partial store: [block][64 rows][128 cols]; C: col=lane&15, row=lg*4+q
    float* pb = Pp + (size_t)blockIdx.x * (BM * BN);
#pragma unroll
    for (int j = 0; j < 2; ++j) {
#pragma unroll
        for (int q = 0; q < 4; ++q) {
            int r = wm * 16 + lg * 4 + q;
            int c = wn * 32 + j * 16 + l15;
            pb[r * BN + c]      = acc[j][q];       // top
            pb[r * BN + c + 64] = acc[j + 2][q];   // down
        }
    }
}

// ---------------- Stage 5: combine K-halves, ratio + mu + bias ------------
__global__ __launch_bounds__(256) void reduce_kernel(
    const float* __restrict__ Pp, const float* __restrict__ bias,
    const float* __restrict__ muptr, float* __restrict__ out)
{
    int idx = blockIdx.x * 256 + threadIdx.x;   // 1M outputs
    int r = idx >> 6, c = idx & 63;
    int rb = r >> 6, rr = r & 63;
    const float* p0 = Pp + (size_t)(rb * 2) * (BM * BN) + rr * BN + c;
    const float* p1 = p0 + BM * BN;
    float T = p0[0]  + p1[0];
    float D = p0[64] + p1[64];
    out[idx] = T / D + muptr[0] + bias[c];
}

extern "C" void kernel_launch(void* const* d_in, const int* in_sizes, int n_in,
                              void* d_out, int out_size, void* d_ws, size_t ws_size,
                              hipStream_t stream)
{
    const float* inp  = (const float*)d_in[0];
    const float* adj  = (const float*)d_in[1];
    const float* W    = (const float*)d_in[2];
    const float* bias = (const float*)d_in[3];
    const int*   p    = (const int*)d_in[4];
    float* out = (float*)d_out;

    // ws layout: Bt 4MB | partmin 1KB | mu | Wt 64KB | (8MB:) Pp 16MB
    char* ws = (char*)d_ws;
    u16*   Bt      = (u16*)ws;
    float* partmin = (float*)(ws + (size_t)4 * 1024 * 1024);
    float* mu      = partmin + 256;
    float* Wt      = (float*)(ws + (size_t)4 * 1024 * 1024 + 4096);
    float* Pp      = (float*)(ws + (size_t)8 * 1024 * 1024);

    float* sup = out;   // park support in d_out; reduce overwrites at the end

    wt_kernel       <<<64,   256, 0, stream>>>(W, Wt);
    support_kernel  <<<512,  256, 0, stream>>>(inp, Wt, sup);
    min_part_kernel <<<256,  256, 0, stream>>>(sup, partmin);
    min_final_kernel<<<1,    256, 0, stream>>>(partmin, mu);
    build_bt_kernel <<<64,   256, 0, stream>>>(sup, mu, p, Bt);
    gemm_kernel     <<<512,  512, 0, stream>>>(adj, Bt, Pp);
    reduce_kernel   <<<4096, 256, 0, stream>>>(Pp, bias, mu, out);
}